// Round 10
// baseline (195.312 us; speedup 1.0000x reference)
//
#include <hip/hip_runtime.h>

// PathEncoder: out[b,x,y,h] = sum_l dot(edata[b, path[b,x,y,l], :], emb[l,h,:]) / clip(dist,1,4)
// Two passes, bf16 intermediate table:
//  Pass 1 (proj_kernel): proj[b,e,j] = dot(edge_feat[b,e,:], W[j,:]) fp32, stored bf16 RNE.
//     v3: thread computes 4 rows x 8 j (wave w owns j-slice w*8..w*8+8). One LDS W-fragment
//     read serves 4 rows -> 128 ds_read_b128/thread (was 512). Thread count unchanged
//     (65552; 4 waves/CU) so VALU stays spread over all SIMDs. Redundant row loads (4
//     threads/row, one per wave) hit L1 (16 KB/chunk working set per block).
//  Pass 2 (gather_kernel): out[gid,h] = (1/denom) * sum_l proj_bf16[b, path_l, l*8+h].
//     Exact round-3 (best measured 84.0us) form: 1 px/thread, XCD-pinned b=blk&15,
//     nontemporal streams for path/dist/out.

#define E_DIM 4096
#define D_DIM 64
#define L_DIM 4
#define H_DIM 8
#define LH 32                   // L*H
#define B_DIM 16
#define NN 16384                // N*N
#define ROWS_PER_B (E_DIM + 1)  // 4097 (includes zero pad row)
#define TOTAL_ROWS (B_DIM * ROWS_PER_B)  // 65552

typedef float f32x4 __attribute__((ext_vector_type(4)));
typedef int   i32x4 __attribute__((ext_vector_type(4)));
typedef unsigned int u32;

__device__ __forceinline__ u32 f32_bits(float f) { return __builtin_bit_cast(u32, f); }
__device__ __forceinline__ float bits_f32(u32 u) { return __builtin_bit_cast(float, u); }

// round-to-nearest-even f32 -> bf16 (low 16 bits)
__device__ __forceinline__ u32 f2bf(float f) {
    u32 x = f32_bits(f);
    return (x + 0x7fffu + ((x >> 16) & 1u)) >> 16;
}

// ---------------- Pass 1: per-edge projection (fp32 math, bf16 store) ------
// grid: ceil(65552/256)=257 blocks; block covers 256 consecutive rows.
// thread (wave w, lane l): rows base+l+{0,64,128,192}, j in [w*8, w*8+8).
__global__ __launch_bounds__(256) void proj_kernel(
    const float* __restrict__ edge_feat,   // [B, E, 64]
    const float* __restrict__ W,           // [32, 64]
    unsigned short* __restrict__ proj)     // [B, E+1, 32] bf16
{
    __shared__ f32x4 Wl[LH * 16];          // 32 rows x 16 f32x4 = 8 KB

    const int tid = threadIdx.x;
    const f32x4* W4 = (const f32x4*)W;     // 512 f32x4 total
    Wl[tid]       = W4[tid];
    Wl[tid + 256] = W4[tid + 256];
    __syncthreads();

    const int w    = tid >> 6;             // wave = j-slice 0..3
    const int l    = tid & 63;
    const int base = blockIdx.x * 256;

    int  r[4];
    bool valid[4], pad[4];
    size_t rowbase[4];
    #pragma unroll
    for (int i = 0; i < 4; ++i) {
        r[i]     = base + l + i * 64;
        valid[i] = r[i] < TOTAL_ROWS;
        int bi   = valid[i] ? (r[i] / ROWS_PER_B) : 0;
        int ei   = valid[i] ? (r[i] - bi * ROWS_PER_B) : 0;
        pad[i]   = (ei == E_DIM);
        rowbase[i] = valid[i] ? ((size_t)bi * E_DIM + (pad[i] ? 0 : ei)) * D_DIM : 0;
    }

    float acc[4][8];
    #pragma unroll
    for (int i = 0; i < 4; ++i)
        #pragma unroll
        for (int jj = 0; jj < 8; ++jj) acc[i][jj] = 0.f;

    for (int c = 0; c < 4; ++c) {          // k-chunk of 16 floats
        f32x4 rowc[4][4];
        #pragma unroll
        for (int i = 0; i < 4; ++i) {
            const f32x4* src = (const f32x4*)(edge_feat + rowbase[i] + c * 16);
            #pragma unroll
            for (int q = 0; q < 4; ++q) rowc[i][q] = src[q];
        }
        #pragma unroll
        for (int jj = 0; jj < 8; ++jj) {
            const int j = w * 8 + jj;      // wave-uniform -> same-addr LDS broadcast
            f32x4 w0 = Wl[j * 16 + c * 4 + 0];
            f32x4 w1 = Wl[j * 16 + c * 4 + 1];
            f32x4 w2 = Wl[j * 16 + c * 4 + 2];
            f32x4 w3 = Wl[j * 16 + c * 4 + 3];
            #pragma unroll
            for (int i = 0; i < 4; ++i) {
                f32x4 t = rowc[i][0] * w0;
                t += rowc[i][1] * w1;
                t += rowc[i][2] * w2;
                t += rowc[i][3] * w3;
                acc[i][jj] += (t.x + t.y) + (t.z + t.w);
            }
        }
    }

    #pragma unroll
    for (int i = 0; i < 4; ++i) {
        if (!valid[i]) continue;
        u32 p0 = f2bf(acc[i][0]) | (f2bf(acc[i][1]) << 16);
        u32 p1 = f2bf(acc[i][2]) | (f2bf(acc[i][3]) << 16);
        u32 p2 = f2bf(acc[i][4]) | (f2bf(acc[i][5]) << 16);
        u32 p3 = f2bf(acc[i][6]) | (f2bf(acc[i][7]) << 16);
        if (pad[i]) { p0 = p1 = p2 = p3 = 0u; }
        i32x4 v = { (int)p0, (int)p1, (int)p2, (int)p3 };
        *(i32x4*)(proj + (size_t)r[i] * LH + w * 8) = v;
    }
}

// ---------------- Pass 2: gather + sum + scale (round-3 form) --------------
__global__ __launch_bounds__(256) void gather_kernel(
    const i32x4* __restrict__ path4,       // [B*N*N] int4 (L=4 packed)
    const int*  __restrict__ dist,         // [B*N*N]
    const unsigned short* __restrict__ proj, // [B, E+1, 32] bf16
    float* __restrict__ out)               // [B*N*N, 8]
{
    const int tid   = threadIdx.x;
    const int blk   = blockIdx.x;          // 1024 blocks
    const int b     = blk & 15;            // graph b pinned to XCD b&7
    const int chunk = blk >> 4;
    const int gid   = (b << 14) | (chunk << 8) | tid;

    i32x4 p = __builtin_nontemporal_load(path4 + gid);
    int  dv = __builtin_nontemporal_load(dist + gid);

    const unsigned short* pb = proj + (size_t)b * ROWS_PER_B * LH;

    // l-th gather: 8 bf16 (16 B) at row path_l, cols l*8..l*8+7 (warm local L2)
    i32x4 A = *(const i32x4*)(pb + (u32)p.x * LH + 0);
    i32x4 Bv= *(const i32x4*)(pb + (u32)p.y * LH + 8);
    i32x4 C = *(const i32x4*)(pb + (u32)p.z * LH + 16);
    i32x4 D = *(const i32x4*)(pb + (u32)p.w * LH + 24);

    dv = dv < 1 ? 1 : (dv > L_DIM ? L_DIM : dv);
    float s = 1.0f / (float)dv;            // exact for 1,2,4; ~1ulp for 3

    float oo[8];
    #pragma unroll
    for (int k = 0; k < 4; ++k) {
        u32 a = (u32)A[k], bb = (u32)Bv[k], c = (u32)C[k], d = (u32)D[k];
        float fe = (bits_f32(a << 16) + bits_f32(bb << 16))
                 + (bits_f32(c << 16) + bits_f32(d << 16));
        float fo = (bits_f32(a & 0xffff0000u) + bits_f32(bb & 0xffff0000u))
                 + (bits_f32(c & 0xffff0000u) + bits_f32(d & 0xffff0000u));
        oo[2*k]   = fe * s;
        oo[2*k+1] = fo * s;
    }
    f32x4 o0 = { oo[0], oo[1], oo[2], oo[3] };
    f32x4 o1 = { oo[4], oo[5], oo[6], oo[7] };

    f32x4* op = (f32x4*)(out + (size_t)gid * 8);
    __builtin_nontemporal_store(o0, op);
    __builtin_nontemporal_store(o1, op + 1);
}

extern "C" void kernel_launch(void* const* d_in, const int* in_sizes, int n_in,
                              void* d_out, int out_size, void* d_ws, size_t ws_size,
                              hipStream_t stream) {
    const float* edge_feat = (const float*)d_in[0];   // [16,4096,64] f32
    const int*   path      = (const int*)  d_in[1];   // [16,128,128,4] i32
    const int*   dist      = (const int*)  d_in[2];   // [16,128,128] i32
    const float* emb_w     = (const float*)d_in[3];   // [32,64] f32

    unsigned short* proj = (unsigned short*)d_ws;     // [16,4097,32] bf16 = 4.2 MB

    proj_kernel<<<(TOTAL_ROWS + 255) / 256, 256, 0, stream>>>(edge_feat, emb_w, proj);

    gather_kernel<<<(B_DIM * NN) / 256, 256, 0, stream>>>(
        (const i32x4*)path, dist, proj, (float*)d_out);
}

// Round 11
// 83.340 us; speedup vs baseline: 2.3436x; 2.3436x over previous
//
#include <hip/hip_runtime.h>

// PathEncoder: out[b,x,y,h] = sum_l dot(edata[b, path[b,x,y,l], :], emb[l,h,:]) / clip(dist,1,4)
// Two passes, bf16 intermediate table:
//  Pass 1 (proj_kernel v4): proj[b,e,j] = dot(edge_feat[b,e,:], W[j,:]) fp32, stored bf16 RNE.
//     4 threads per row (tid&3 = 8-wide j-slice, tid>>2 = row): 1025 blocks = 4 blocks/CU
//     = 16 waves/CU (v3 lesson: old 257-block grid was 1 block/CU, grid-starved).
//     Row redundancy is INTRA-wave (4 adjacent lanes share a row -> coalescer merges;
//     v3's cross-wave redundancy caused 9x over-fetch, 151 MB). LDS reads 128/thread
//     (was 512); W skewed by +js*16B (Wl[i+(i>>7)]) so the 4 concurrent broadcast
//     addresses hit disjoint bank quads.
//  Pass 2 (gather_kernel): r3-exact (best measured 84.0us): 1 px/thread, XCD-pinned
//     b=blk&15, nontemporal path/dist/out streams, 16 B bf16 gathers from warm L2.

#define E_DIM 4096
#define D_DIM 64
#define L_DIM 4
#define H_DIM 8
#define LH 32                   // L*H
#define B_DIM 16
#define NN 16384                // N*N
#define ROWS_PER_B (E_DIM + 1)  // 4097 (includes zero pad row)
#define TOTAL_ROWS (B_DIM * ROWS_PER_B)  // 65552

typedef float f32x4 __attribute__((ext_vector_type(4)));
typedef int   i32x4 __attribute__((ext_vector_type(4)));
typedef unsigned int u32;

__device__ __forceinline__ u32 f32_bits(float f) { return __builtin_bit_cast(u32, f); }
__device__ __forceinline__ float bits_f32(u32 u) { return __builtin_bit_cast(float, u); }

// round-to-nearest-even f32 -> bf16 (low 16 bits)
__device__ __forceinline__ u32 f2bf(float f) {
    u32 x = f32_bits(f);
    return (x + 0x7fffu + ((x >> 16) & 1u)) >> 16;
}

// ---------------- Pass 1: per-edge projection (fp32 math, bf16 store) ------
// grid: ceil(65552/64) = 1025 blocks; block covers 64 rows x 4 j-slices.
__global__ __launch_bounds__(256) void proj_kernel(
    const float* __restrict__ edge_feat,   // [B, E, 64]
    const float* __restrict__ W,           // [32, 64]
    unsigned short* __restrict__ proj)     // [B, E+1, 32] bf16
{
    // W staged with js-skew: logical idx i = j*16+d4 stored at i + (i>>7)
    // -> the 4 j-slices' broadcast reads land on disjoint bank quads.
    __shared__ f32x4 Wl[LH * 16 + 4];      // 8.06 KB

    const int tid = threadIdx.x;
    const f32x4* W4 = (const f32x4*)W;     // 512 f32x4 total
    {
        int i0 = tid;
        int i1 = tid + 256;
        Wl[i0 + (i0 >> 7)] = W4[i0];
        Wl[i1 + (i1 >> 7)] = W4[i1];
    }
    __syncthreads();

    const int js = tid & 3;                // j-slice: j in [js*8, js*8+8)
    const int rl = tid >> 2;               // row within block, 0..63
    const int r  = blockIdx.x * 64 + rl;
    if (r >= TOTAL_ROWS) return;
    const int b = r / ROWS_PER_B;
    const int e = r - b * ROWS_PER_B;

    i32x4* outp = (i32x4*)(proj + (size_t)r * LH + js * 8);  // this thread's 16 B

    if (e == E_DIM) {                      // zero pad row
        *outp = (i32x4)0;
        return;
    }

    // 4 adjacent lanes load the same row -> merged by the coalescer (intra-wave).
    const f32x4* row4 = (const f32x4*)(edge_feat + ((size_t)b * E_DIM + e) * D_DIM);
    f32x4 row[16];
    #pragma unroll
    for (int i = 0; i < 16; ++i) row[i] = row4[i];

    const int jbase = js * 8;
    u32 pk[4];
    #pragma unroll
    for (int jp = 0; jp < 4; ++jp) {       // 2 j's per iter
        const int j0 = jbase + jp * 2;
        const int j1 = j0 + 1;
        f32x4 a0 = (f32x4)0.f, a1 = (f32x4)0.f;
        #pragma unroll
        for (int d4 = 0; d4 < 16; ++d4) {
            a0 += row[d4] * Wl[j0 * 16 + d4 + js];   // skewed, conflict-free broadcast
            a1 += row[d4] * Wl[j1 * 16 + d4 + js];
        }
        float s0 = (a0.x + a0.y) + (a0.z + a0.w);
        float s1 = (a1.x + a1.y) + (a1.z + a1.w);
        pk[jp] = f2bf(s0) | (f2bf(s1) << 16);
    }
    i32x4 v = { (int)pk[0], (int)pk[1], (int)pk[2], (int)pk[3] };
    *outp = v;
}

// ---------------- Pass 2: gather + sum + scale (round-3 form) --------------
__global__ __launch_bounds__(256) void gather_kernel(
    const i32x4* __restrict__ path4,       // [B*N*N] int4 (L=4 packed)
    const int*  __restrict__ dist,         // [B*N*N]
    const unsigned short* __restrict__ proj, // [B, E+1, 32] bf16
    float* __restrict__ out)               // [B*N*N, 8]
{
    const int tid   = threadIdx.x;
    const int blk   = blockIdx.x;          // 1024 blocks
    const int b     = blk & 15;            // graph b pinned to XCD b&7
    const int chunk = blk >> 4;
    const int gid   = (b << 14) | (chunk << 8) | tid;

    i32x4 p = __builtin_nontemporal_load(path4 + gid);
    int  dv = __builtin_nontemporal_load(dist + gid);

    const unsigned short* pb = proj + (size_t)b * ROWS_PER_B * LH;

    // l-th gather: 8 bf16 (16 B) at row path_l, cols l*8..l*8+7 (warm local L2)
    i32x4 A = *(const i32x4*)(pb + (u32)p.x * LH + 0);
    i32x4 Bv= *(const i32x4*)(pb + (u32)p.y * LH + 8);
    i32x4 C = *(const i32x4*)(pb + (u32)p.z * LH + 16);
    i32x4 D = *(const i32x4*)(pb + (u32)p.w * LH + 24);

    dv = dv < 1 ? 1 : (dv > L_DIM ? L_DIM : dv);
    float s = 1.0f / (float)dv;            // exact for 1,2,4; ~1ulp for 3

    float oo[8];
    #pragma unroll
    for (int k = 0; k < 4; ++k) {
        u32 a = (u32)A[k], bb = (u32)Bv[k], c = (u32)C[k], d = (u32)D[k];
        float fe = (bits_f32(a << 16) + bits_f32(bb << 16))
                 + (bits_f32(c << 16) + bits_f32(d << 16));
        float fo = (bits_f32(a & 0xffff0000u) + bits_f32(bb & 0xffff0000u))
                 + (bits_f32(c & 0xffff0000u) + bits_f32(d & 0xffff0000u));
        oo[2*k]   = fe * s;
        oo[2*k+1] = fo * s;
    }
    f32x4 o0 = { oo[0], oo[1], oo[2], oo[3] };
    f32x4 o1 = { oo[4], oo[5], oo[6], oo[7] };

    f32x4* op = (f32x4*)(out + (size_t)gid * 8);
    __builtin_nontemporal_store(o0, op);
    __builtin_nontemporal_store(o1, op + 1);
}

extern "C" void kernel_launch(void* const* d_in, const int* in_sizes, int n_in,
                              void* d_out, int out_size, void* d_ws, size_t ws_size,
                              hipStream_t stream) {
    const float* edge_feat = (const float*)d_in[0];   // [16,4096,64] f32
    const int*   path      = (const int*)  d_in[1];   // [16,128,128,4] i32
    const int*   dist      = (const int*)  d_in[2];   // [16,128,128] i32
    const float* emb_w     = (const float*)d_in[3];   // [32,64] f32

    unsigned short* proj = (unsigned short*)d_ws;     // [16,4097,32] bf16 = 4.2 MB

    proj_kernel<<<(TOTAL_ROWS + 63) / 64, 256, 0, stream>>>(edge_feat, emb_w, proj);

    gather_kernel<<<(B_DIM * NN) / 256, 256, 0, stream>>>(
        (const i32x4*)path, dist, proj, (float*)d_out);
}

// Round 15
// 80.783 us; speedup vs baseline: 2.4177x; 1.0317x over previous
//
#include <hip/hip_runtime.h>

// PathEncoder: out[b,x,y,h] = sum_l dot(edata[b, path[b,x,y,l], :], emb[l,h,:]) / clip(dist,1,4)
// Two passes, bf16 intermediate table:
//  Pass 1 (proj_kernel v5, MFMA): proj = edge_feat[65552x64] . W^T[64x32] via
//     mfma_f32_16x16x32_bf16. One wave = one 16-row tile = 4 MFMAs; B-frags (W^T)
//     built once per wave and reused over 2 grid-strided tiles. ZERO LDS (r11 lesson:
//     device-total ds_read count was invariant across r3/v4 reshuffles ~10us; the fix
//     is eliminating per-row LDS work, not redistributing it).
//     Layouts (m89/m91-verified family): A row=lane&15,k=(lane>>4)*8+i; B col=lane&15,
//     same k (B[k,col]=W[col,k] -> lane reads 8 consecutive k of W row col -- contiguous
//     16B); C/D col=lane&15,row=(lane>>4)*4+reg. Pad rows zeroed at store.
//  Pass 2 (gather_kernel): r3-exact (best measured): 1 px/thread, XCD-pinned b=blk&15,
//     nontemporal path/dist/out streams, 16 B bf16 gathers from warm L2.

#define E_DIM 4096
#define D_DIM 64
#define L_DIM 4
#define H_DIM 8
#define LH 32                   // L*H
#define B_DIM 16
#define NN 16384                // N*N
#define ROWS_PER_B (E_DIM + 1)  // 4097 (includes zero pad row)
#define TOTAL_ROWS (B_DIM * ROWS_PER_B)   // 65552 = 4097 * 16 exactly
#define N_TILES (TOTAL_ROWS / 16)         // 4097 16-row tiles
#define P1_BLOCKS 513                     // 513*4 = 2052 waves, 2 tiles each >= 4097
#define P1_WAVES (P1_BLOCKS * 4)

typedef float f32x4 __attribute__((ext_vector_type(4)));
typedef int   i32x4 __attribute__((ext_vector_type(4)));
typedef short s16x8 __attribute__((ext_vector_type(8)));
typedef unsigned int u32;

__device__ __forceinline__ u32 f32_bits(float f) { return __builtin_bit_cast(u32, f); }
__device__ __forceinline__ float bits_f32(u32 u) { return __builtin_bit_cast(float, u); }

// round-to-nearest-even f32 -> bf16 (low 16 bits)
__device__ __forceinline__ u32 f2bf(float f) {
    u32 x = f32_bits(f);
    return (x + 0x7fffu + ((x >> 16) & 1u)) >> 16;
}

// pack 8 f32 -> 8 bf16 (RNE) as an MFMA operand fragment
__device__ __forceinline__ s16x8 pack_bf16x8(f32x4 lo, f32x4 hi) {
    u32 q0 = f2bf(lo.x) | (f2bf(lo.y) << 16);
    u32 q1 = f2bf(lo.z) | (f2bf(lo.w) << 16);
    u32 q2 = f2bf(hi.x) | (f2bf(hi.y) << 16);
    u32 q3 = f2bf(hi.z) | (f2bf(hi.w) << 16);
    i32x4 q = { (int)q0, (int)q1, (int)q2, (int)q3 };
    return __builtin_bit_cast(s16x8, q);
}

// ---------------- Pass 1: per-edge projection via MFMA ----------------
__global__ __launch_bounds__(256) void proj_kernel(
    const float* __restrict__ edge_feat,   // [B, E, 64]
    const float* __restrict__ W,           // [32, 64]
    unsigned short* __restrict__ proj)     // [B, E+1, 32] bf16
{
    const int wid  = threadIdx.x >> 6;             // wave in block
    const int lane = threadIdx.x & 63;
    const int wgid = blockIdx.x * 4 + wid;         // 0..2051
    const int lr   = lane & 15;                    // A-row / B-col / D-col
    const int k0   = (lane >> 4) * 8;              // k-group base

    // B fragments: B[k, col] = W[col, k]; lane reads W[jt*16+lr][kt*32+k0 .. +8]
    s16x8 bf[2][2];
    #pragma unroll
    for (int jt = 0; jt < 2; ++jt)
        #pragma unroll
        for (int kt = 0; kt < 2; ++kt) {
            const float* ws = W + (jt * 16 + lr) * 64 + kt * 32 + k0;
            bf[jt][kt] = pack_bf16x8(*(const f32x4*)ws, *(const f32x4*)(ws + 4));
        }

    #pragma unroll
    for (int tt = 0; tt < 2; ++tt) {
        const int tile = wgid + tt * P1_WAVES;
        if (tile >= N_TILES) break;                // wave-uniform
        const int row0 = tile * 16;

        // A fragments: row = row0+lr, k = k0+i (+32 for 2nd K-tile)
        int ra = row0 + lr;
        int ba = ra / ROWS_PER_B;
        int ea = ra - ba * ROWS_PER_B;
        if (ea == E_DIM) ea = 0;                   // pad row -> dummy data, zeroed at store
        const float* as = edge_feat + ((size_t)ba * E_DIM + ea) * D_DIM + k0;
        s16x8 af0 = pack_bf16x8(*(const f32x4*)as,        *(const f32x4*)(as + 4));
        s16x8 af1 = pack_bf16x8(*(const f32x4*)(as + 32), *(const f32x4*)(as + 36));

        f32x4 acc0 = (f32x4)0.f, acc1 = (f32x4)0.f;
        acc0 = __builtin_amdgcn_mfma_f32_16x16x32_bf16(af0, bf[0][0], acc0, 0, 0, 0);
        acc0 = __builtin_amdgcn_mfma_f32_16x16x32_bf16(af1, bf[0][1], acc0, 0, 0, 0);
        acc1 = __builtin_amdgcn_mfma_f32_16x16x32_bf16(af0, bf[1][0], acc1, 0, 0, 0);
        acc1 = __builtin_amdgcn_mfma_f32_16x16x32_bf16(af1, bf[1][1], acc1, 0, 0, 0);

        // store: D row = row0 + (lane>>4)*4 + reg, cols lr and 16+lr
        const int rbase = row0 + (lane >> 4) * 4;
        #pragma unroll
        for (int reg = 0; reg < 4; ++reg) {
            int rg = rbase + reg;
            int bg = rg / ROWS_PER_B;
            int eg = rg - bg * ROWS_PER_B;
            unsigned short v0 = (unsigned short)f2bf(acc0[reg]);
            unsigned short v1 = (unsigned short)f2bf(acc1[reg]);
            if (eg == E_DIM) { v0 = 0; v1 = 0; }   // pad row -> zeros
            proj[(size_t)rg * LH + lr]      = v0;
            proj[(size_t)rg * LH + 16 + lr] = v1;
        }
    }
}

// ---------------- Pass 2: gather + sum + scale (round-3 form) --------------
__global__ __launch_bounds__(256) void gather_kernel(
    const i32x4* __restrict__ path4,       // [B*N*N] int4 (L=4 packed)
    const int*  __restrict__ dist,         // [B*N*N]
    const unsigned short* __restrict__ proj, // [B, E+1, 32] bf16
    float* __restrict__ out)               // [B*N*N, 8]
{
    const int tid   = threadIdx.x;
    const int blk   = blockIdx.x;          // 1024 blocks
    const int b     = blk & 15;            // graph b pinned to XCD b&7
    const int chunk = blk >> 4;
    const int gid   = (b << 14) | (chunk << 8) | tid;

    i32x4 p = __builtin_nontemporal_load(path4 + gid);
    int  dv = __builtin_nontemporal_load(dist + gid);

    const unsigned short* pb = proj + (size_t)b * ROWS_PER_B * LH;

    // l-th gather: 8 bf16 (16 B) at row path_l, cols l*8..l*8+7 (warm local L2)
    i32x4 A = *(const i32x4*)(pb + (u32)p.x * LH + 0);
    i32x4 Bv= *(const i32x4*)(pb + (u32)p.y * LH + 8);
    i32x4 C = *(const i32x4*)(pb + (u32)p.z * LH + 16);
    i32x4 D = *(const i32x4*)(pb + (u32)p.w * LH + 24);

    dv = dv < 1 ? 1 : (dv > L_DIM ? L_DIM : dv);
    float s = 1.0f / (float)dv;            // exact for 1,2,4; ~1ulp for 3

    float oo[8];
    #pragma unroll
    for (int k = 0; k < 4; ++k) {
        u32 a = (u32)A[k], bb = (u32)Bv[k], c = (u32)C[k], d = (u32)D[k];
        float fe = (bits_f32(a << 16) + bits_f32(bb << 16))
                 + (bits_f32(c << 16) + bits_f32(d << 16));
        float fo = (bits_f32(a & 0xffff0000u) + bits_f32(bb & 0xffff0000u))
                 + (bits_f32(c & 0xffff0000u) + bits_f32(d & 0xffff0000u));
        oo[2*k]   = fe * s;
        oo[2*k+1] = fo * s;
    }
    f32x4 o0 = { oo[0], oo[1], oo[2], oo[3] };
    f32x4 o1 = { oo[4], oo[5], oo[6], oo[7] };

    f32x4* op = (f32x4*)(out + (size_t)gid * 8);
    __builtin_nontemporal_store(o0, op);
    __builtin_nontemporal_store(o1, op + 1);
}

extern "C" void kernel_launch(void* const* d_in, const int* in_sizes, int n_in,
                              void* d_out, int out_size, void* d_ws, size_t ws_size,
                              hipStream_t stream) {
    const float* edge_feat = (const float*)d_in[0];   // [16,4096,64] f32
    const int*   path      = (const int*)  d_in[1];   // [16,128,128,4] i32
    const int*   dist      = (const int*)  d_in[2];   // [16,128,128] i32
    const float* emb_w     = (const float*)d_in[3];   // [32,64] f32

    unsigned short* proj = (unsigned short*)d_ws;     // [16,4097,32] bf16 = 4.2 MB

    proj_kernel<<<P1_BLOCKS, 256, 0, stream>>>(edge_feat, emb_w, proj);

    gather_kernel<<<(B_DIM * NN) / 256, 256, 0, stream>>>(
        (const i32x4*)path, dist, proj, (float*)d_out);
}